// Round 4
// baseline (8005.981 us; speedup 1.0000x reference)
//
#include <hip/hip_runtime.h>
#include <math.h>

// DGM edge sampler, N=8192, DIN=512, DEMB=256, K=16.
// ALL-F32 canonical pipeline: the reference (np recompute of the jax graph)
// keeps float32 dtypes throughout; rank flips vs an "exact" f64 pipeline are
// expected (~1 per dataset, observed as the constant absmax=576 in rounds 1-3).
// We therefore reproduce canonical f32 semantics: k-ascending FMA GEMMs
// (BLAS/XLA microkernel order), numpy-pairwise row sums, explicit __f*_rn
// rounding at every reference op boundary, and rank by the f32 scores.

#define NN 8192
#define DI 512
#define DE 256
#define TK 16

// ---------------- K1: xw = f32(x @ W), k-ascending FMA ----------------
__global__ __launch_bounds__(256) void k_xw32(const float* __restrict__ x,
                                              const float* __restrict__ W,
                                              float* __restrict__ xw) {
  __shared__ float xs[8][DI]; // 16KB
  const int r0 = blockIdx.x * 8;
  const int tid = threadIdx.x;
  for (int t = tid; t < 8 * DI; t += 256)
    xs[t >> 9][t & 511] = x[(size_t)(r0 + (t >> 9)) * DI + (t & 511)];
  __syncthreads();
  float acc[8] = {};
  for (int d = 0; d < DI; ++d) {
    const float w = W[(size_t)d * DE + tid];
#pragma unroll
    for (int r = 0; r < 8; ++r) acc[r] = __fmaf_rn(xs[r][d], w, acc[r]);
  }
  for (int r = 0; r < 8; ++r) xw[(size_t)(r0 + r) * DE + tid] = acc[r];
}

// ---------------- K2: hb = relu(A @ xw), f32 k-ascending FMA ----------------
#define HM 128
#define HN 128
#define HK 16
__global__ __launch_bounds__(256) void k_h32(const float* __restrict__ A,
                                             const float* __restrict__ xw,
                                             float* __restrict__ hb) {
  __shared__ float As[HM][HK + 1]; // 8.7KB
  __shared__ float Bs[HK][HN + 1]; // 8.3KB
  const int i0 = blockIdx.x * HM;
  const int c0 = blockIdx.y * HN;
  const int tid = threadIdx.x;
  const int tc = tid & 15;  // col group
  const int tr = tid >> 4;  // row group
  float acc[8][8] = {};
  for (int k0 = 0; k0 < NN; k0 += HK) {
    for (int t = tid; t < HM * HK; t += 256)
      As[t >> 4][t & 15] = A[(size_t)(i0 + (t >> 4)) * NN + k0 + (t & 15)];
    for (int t = tid; t < HK * HN; t += 256)
      Bs[t >> 7][t & 127] = xw[(size_t)(k0 + (t >> 7)) * DE + c0 + (t & 127)];
    __syncthreads();
    for (int k = 0; k < HK; ++k) {
      float a[8], b[8];
#pragma unroll
      for (int u = 0; u < 8; ++u) a[u] = As[tr * 8 + u][k];
#pragma unroll
      for (int m = 0; m < 8; ++m) b[m] = Bs[k][tc + 16 * m];
#pragma unroll
      for (int u = 0; u < 8; ++u)
#pragma unroll
        for (int m = 0; m < 8; ++m) acc[u][m] = __fmaf_rn(a[u], b[m], acc[u][m]);
    }
    __syncthreads();
  }
  for (int u = 0; u < 8; ++u) {
    const int i = i0 + tr * 8 + u;
    for (int m = 0; m < 8; ++m) {
      const int j = c0 + tc + 16 * m;
      hb[(size_t)i * DE + j] = fmaxf(acc[u][m], 0.0f);
    }
  }
}

// ---------------- K3: sq[i] = sum(h_i * h_i), numpy-pairwise structure ----------------
// np pairwise_sum(256) = pairwise(0..127) + pairwise(128..255); each half:
// 8 stride-interleaved partials then ((p0+p1)+(p2+p3))+((p4+p5)+(p6+p7)).
__global__ __launch_bounds__(256) void k_sq32(const float* __restrict__ hb,
                                              float* __restrict__ sq) {
  const int row = blockIdx.x * 256 + threadIdx.x;
  const float* h = hb + (size_t)row * DE;
  float half[2];
#pragma unroll
  for (int hx = 0; hx < 2; ++hx) {
    float p[8] = {};
    for (int t = 0; t < 16; ++t) {
#pragma unroll
      for (int m = 0; m < 8; ++m) {
        const float v = h[hx * 128 + t * 8 + m];
        p[m] = __fadd_rn(p[m], __fmul_rn(v, v)); // h*h rounded, then summed
      }
    }
    const float t01 = __fadd_rn(p[0], p[1]), t23 = __fadd_rn(p[2], p[3]);
    const float t45 = __fadd_rn(p[4], p[5]), t67 = __fadd_rn(p[6], p[7]);
    half[hx] = __fadd_rn(__fadd_rn(t01, t23), __fadd_rn(t45, t67));
  }
  sq[row] = __fadd_rn(half[0], half[1]);
}

// ---------------- K4: fused f32 scoring + exact streaming top-16 ----------------
// s(i,j) = nv - D*C with nv = logf(-logf(q+1e-8f)),
// D = max((sqi+sqj) - 2*dot, 0), all ops rounded exactly as the reference.
// Selection: ascending-j streaming top-16, strict-greater insert, evict
// (min value, largest index) => exact lax.top_k (value desc, index asc).
__global__ __launch_bounds__(256) void k_sel(const float* __restrict__ hb,
                                             const float* __restrict__ sq,
                                             const float* __restrict__ q,
                                             const float* __restrict__ temp,
                                             float* __restrict__ out) {
  __shared__ float Ha[32][33];    // 4.2KB
  __shared__ float Hb[128][33];   // 16.9KB
  __shared__ float tile[32][129]; // 16.5KB
  __shared__ float sval[32][TK];  // 2KB
  __shared__ int   sidx[32][TK];  // 2KB
  const int i0 = blockIdx.x * 32;
  const int tid = threadIdx.x;
  const int cr = tid & 15;  // col group: cols cr*8..cr*8+7
  const int rr = tid >> 4;  // row pair: rows rr*2, rr*2+1
  if (tid < 32) {
#pragma unroll
    for (int u = 0; u < TK; ++u) { sval[tid][u] = -3.0e38f; sidx[tid][u] = 0x7fffffff; }
  }
  const float tt = fminf(fmaxf(temp[0], -5.0f), 5.0f);
  const float C = expf(tt);
  float sqi[2];
  sqi[0] = sq[i0 + rr * 2];
  sqi[1] = sq[i0 + rr * 2 + 1];
  float cmin = -3.0e38f; // selection threads' current 16th-best
  __syncthreads();

  for (int j0 = 0; j0 < NN; j0 += 128) {
    float acc[2][8] = {};
    for (int k0 = 0; k0 < DE; k0 += 32) {
      for (int t = tid; t < 32 * 32; t += 256)
        Ha[t >> 5][t & 31] = hb[(size_t)(i0 + (t >> 5)) * DE + k0 + (t & 31)];
      for (int t = tid; t < 128 * 32; t += 256)
        Hb[t >> 5][t & 31] = hb[(size_t)(j0 + (t >> 5)) * DE + k0 + (t & 31)];
      __syncthreads();
      for (int k = 0; k < 32; ++k) {
        const float a0 = Ha[rr * 2][k];
        const float a1 = Ha[rr * 2 + 1][k];
#pragma unroll
        for (int m = 0; m < 8; ++m) {
          const float b = Hb[cr * 8 + m][k];
          acc[0][m] = __fmaf_rn(a0, b, acc[0][m]);
          acc[1][m] = __fmaf_rn(a1, b, acc[1][m]);
        }
      }
      __syncthreads();
    }
#pragma unroll
    for (int rl = 0; rl < 2; ++rl) {
      const int i = i0 + rr * 2 + rl;
      const float* qrow = q + (size_t)i * NN;
#pragma unroll
      for (int m = 0; m < 8; ++m) {
        const int j = j0 + cr * 8 + m;
        const float t1 = __fadd_rn(sqi[rl], sq[j]);      // sq_i + sq_j
        float D = __fsub_rn(t1, 2.0f * acc[rl][m]);      // - 2*dot (x2 exact)
        D = fmaxf(D, 0.0f);
        const float lg = __fmul_rn(D, C);                // logits = D*exp(t)
        const float p = __fadd_rn(qrow[j], 1e-8f);
        const float u = logf(p);
        const float nv = logf(-u);                       // log(-log(q+1e-8))
        tile[rr * 2 + rl][cr * 8 + m] = __fsub_rn(nv, lg); // -lq
      }
    }
    __syncthreads();
    if (tid < 32) {
      const int r = tid;
      for (int c = 0; c < 128; ++c) {
        const float v = tile[r][c];
        if (v > cmin) { // strict: equal value w/ larger j loses (index-asc ties)
          float mv = 3.0e38f; int mi = -1, ms = 0;
#pragma unroll
          for (int u = 0; u < TK; ++u) {
            const float su = sval[r][u]; const int iu = sidx[r][u];
            if (su < mv || (su == mv && iu > mi)) { mv = su; mi = iu; ms = u; }
          }
          sval[r][ms] = v; sidx[r][ms] = j0 + c;
          float nm = 3.0e38f;
#pragma unroll
          for (int u = 0; u < TK; ++u) nm = fminf(nm, sval[r][u]);
          cmin = nm;
        }
      }
    }
    __syncthreads();
  }

  // final per-row sort (value desc, index asc) + output
  if (tid < 32) {
    const int r = tid, i = i0 + r;
    float* E0 = out + (size_t)NN * DE;  // neighbor indices
    float* E1 = E0 + (size_t)NN * TK;   // source rows
    float* LP = E1 + (size_t)NN * TK;   // logprobs
    for (int it = 0; it < TK; ++it) {
      float bv = -3.0e38f; int bj = 0x7fffffff, bs = 0;
#pragma unroll
      for (int u = 0; u < TK; ++u) {
        const float su = sval[r][u]; const int iu = sidx[r][u];
        if (su > bv || (su == bv && iu < bj)) { bv = su; bj = iu; bs = u; }
      }
      E0[(size_t)i * TK + it] = (float)bj;
      E1[(size_t)i * TK + it] = (float)i;
      LP[(size_t)i * TK + it] = bv;
      sval[r][bs] = -3.0e38f; sidx[r][bs] = 0x7fffffff;
    }
  }
}

extern "C" void kernel_launch(void* const* d_in, const int* in_sizes, int n_in,
                              void* d_out, int out_size, void* d_ws, size_t ws_size,
                              hipStream_t stream) {
  const float* x    = (const float*)d_in[0];
  const float* A    = (const float*)d_in[1];
  const float* W    = (const float*)d_in[2];
  const float* temp = (const float*)d_in[3];
  const float* q    = (const float*)d_in[4];
  float* out = (float*)d_out;

  char* ws = (char*)d_ws;
  float* xw = (float*)(ws);             // 8,388,608 B
  float* sq = (float*)(ws + 8388608);   //    32,768 B

  float* hb = out; // [N, DE] f32 output region holds h

  hipLaunchKernelGGL(k_xw32, dim3(NN / 8),          dim3(256), 0, stream, x, W, xw);
  hipLaunchKernelGGL(k_h32,  dim3(NN / HM, DE / HN), dim3(256), 0, stream, A, xw, hb);
  hipLaunchKernelGGL(k_sq32, dim3(NN / 256),        dim3(256), 0, stream, hb, sq);
  hipLaunchKernelGGL(k_sel,  dim3(NN / 32),         dim3(256), 0, stream, hb, sq, q, temp, out);
}

// Round 5
// 2676.655 us; speedup vs baseline: 2.9910x; 2.9910x over previous
//
#include <hip/hip_runtime.h>
#include <math.h>

// DGM edge sampler, N=8192, DIN=512, DEMB=256, K=16.
// Canonical-f32 pipeline (bit-faithful to the np reference): k-ascending FMA
// GEMMs, numpy-pairwise row sums, explicit __f*_rn at every op boundary.
// Round 5: register-blocked b128 GEMMs + swizzled LDS + parallel top-16.

#define NN 8192
#define DI 512
#define DE 256
#define TK 16

typedef float4 f4;

// ======== K1/K2: C = [relu](Amat @ Bmat), Bmat is [KTOT][256] ========
// block: 32 rows x 256 cols, 512 threads. thread: 2 rows x 8 cols (m-split).
template <int KTOT, bool RELU>
__global__ __launch_bounds__(512) void k_gemm(const float* __restrict__ Amat, int lda,
                                              const float* __restrict__ Bmat,
                                              float* __restrict__ Cout) {
  __shared__ float As[32][32];   // 4 KB
  __shared__ float Bs[32][256];  // 32 KB
  const int i0 = blockIdx.x * 32;
  const int tid = threadIdx.x;
  const int g = tid >> 5;   // 0..15 -> rows g*2, g*2+1
  const int cg = tid & 31;  // cols cg*4..+3 and 128+cg*4..+3
  const int arow = tid >> 3, aq = tid & 7;  // A staging (tid<256)
  const int bkk = tid >> 4, bq = tid & 15;  // B staging
  float acc[2][8] = {};
  f4 pa;
  f4 pb[4];
  if (tid < 256) pa = *(const f4*)&Amat[(size_t)(i0 + arow) * lda + aq * 4];
#pragma unroll
  for (int l = 0; l < 4; ++l)
    pb[l] = *(const f4*)&Bmat[(size_t)bkk * DE + (bq + 16 * l) * 4];

  for (int k0 = 0; k0 < KTOT; k0 += 32) {
    __syncthreads();
    if (tid < 256) *(f4*)&As[arow][aq * 4] = pa;
#pragma unroll
    for (int l = 0; l < 4; ++l) *(f4*)&Bs[bkk][(bq + 16 * l) * 4] = pb[l];
    if (k0 + 32 < KTOT) {
      if (tid < 256) pa = *(const f4*)&Amat[(size_t)(i0 + arow) * lda + k0 + 32 + aq * 4];
#pragma unroll
      for (int l = 0; l < 4; ++l)
        pb[l] = *(const f4*)&Bmat[(size_t)(k0 + 32 + bkk) * DE + (bq + 16 * l) * 4];
    }
    __syncthreads();
#pragma unroll
    for (int k4 = 0; k4 < 8; ++k4) {
      f4 a0 = *(const f4*)&As[g * 2 + 0][k4 * 4];
      f4 a1 = *(const f4*)&As[g * 2 + 1][k4 * 4];
      const float* a0f = (const float*)&a0;
      const float* a1f = (const float*)&a1;
#pragma unroll
      for (int qq = 0; qq < 4; ++qq) {
        f4 b0 = *(const f4*)&Bs[k4 * 4 + qq][cg * 4];
        f4 b1 = *(const f4*)&Bs[k4 * 4 + qq][128 + cg * 4];
        const float* b0f = (const float*)&b0;
        const float* b1f = (const float*)&b1;
#pragma unroll
        for (int m = 0; m < 4; ++m) {
          acc[0][m] = __fmaf_rn(a0f[qq], b0f[m], acc[0][m]);
          acc[1][m] = __fmaf_rn(a1f[qq], b0f[m], acc[1][m]);
          acc[0][4 + m] = __fmaf_rn(a0f[qq], b1f[m], acc[0][4 + m]);
          acc[1][4 + m] = __fmaf_rn(a1f[qq], b1f[m], acc[1][4 + m]);
        }
      }
    }
  }
#pragma unroll
  for (int u = 0; u < 2; ++u) {
    const int i = i0 + g * 2 + u;
    f4 o0, o1;
    float* o0f = (float*)&o0;
    float* o1f = (float*)&o1;
#pragma unroll
    for (int m = 0; m < 4; ++m) {
      o0f[m] = RELU ? fmaxf(acc[u][m], 0.0f) : acc[u][m];
      o1f[m] = RELU ? fmaxf(acc[u][4 + m], 0.0f) : acc[u][4 + m];
    }
    *(f4*)&Cout[(size_t)i * DE + cg * 4] = o0;
    *(f4*)&Cout[(size_t)i * DE + 128 + cg * 4] = o1;
  }
}

// ======== K3: sq[i] = sum(h_i*h_i), numpy-pairwise structure ========
__global__ __launch_bounds__(256) void k_sq32(const float* __restrict__ hb,
                                              float* __restrict__ sq) {
  const int row = blockIdx.x * 256 + threadIdx.x;
  const float* h = hb + (size_t)row * DE;
  float half[2];
#pragma unroll
  for (int hx = 0; hx < 2; ++hx) {
    float p[8] = {};
    for (int t = 0; t < 16; ++t) {
      f4 v0 = *(const f4*)&h[hx * 128 + t * 8];
      f4 v1 = *(const f4*)&h[hx * 128 + t * 8 + 4];
      const float* v0f = (const float*)&v0;
      const float* v1f = (const float*)&v1;
#pragma unroll
      for (int m = 0; m < 4; ++m) {
        p[m] = __fadd_rn(p[m], __fmul_rn(v0f[m], v0f[m]));
        p[4 + m] = __fadd_rn(p[4 + m], __fmul_rn(v1f[m], v1f[m]));
      }
    }
    const float t01 = __fadd_rn(p[0], p[1]), t23 = __fadd_rn(p[2], p[3]);
    const float t45 = __fadd_rn(p[4], p[5]), t67 = __fadd_rn(p[6], p[7]);
    half[hx] = __fadd_rn(__fadd_rn(t01, t23), __fadd_rn(t45, t67));
  }
  sq[row] = __fadd_rn(half[0], half[1]);
}

// ======== K4: fused f32 scoring + parallel streaming top-16 ========
// block: 32 rows, 512 threads, j-tile 256, k-subtile 32 (8 sub/tile, 256 steps).
// compute thread: 1 row (g=tid>>4) x 16 cols (cg*4 + 64*mb + e).
// selector thread: (r=tid>>4, s=tid&15), scans j = c*16+s ascending, keeps a
// register-resident sorted top-16 (compile-time-indexed shift insert).
__global__ __launch_bounds__(512) void k_sel(const float* __restrict__ hb,
                                             const float* __restrict__ sqv,
                                             const float* __restrict__ q,
                                             const float* __restrict__ temp,
                                             float* __restrict__ out) {
  __shared__ float Ha[32][256];   // 32 KB (merge area pt1 at end)
  __shared__ float Hb[256][32];   // 32 KB, quad-swizzled (merge pt2 at end)
  __shared__ float sc[32][260];   // 33.3 KB scores
  __shared__ int curs[32][16];    // 2 KB merge cursors
  const int i0 = blockIdx.x * 32;
  const int tid = threadIdx.x;
  const int g = tid >> 4;    // compute/score row 0..31; also selector row
  const int cg = tid & 15;   // compute col group; also selector sub-index
  const int jrow = tid >> 1, half = tid & 1;  // Hb staging
  const int swzc = cg >> 1;  // == (jl>>3)&7 for all this thread's jl

  // Ha: 32 rows x 256 once
  {
    const int row = tid >> 4, part = tid & 15;
#pragma unroll
    for (int w = 0; w < 4; ++w)
      *(f4*)&Ha[row][part * 16 + w * 4] =
          *(const f4*)&hb[(size_t)(i0 + row) * DE + part * 16 + w * 4];
  }
  const float tt = fminf(fmaxf(temp[0], -5.0f), 5.0f);
  const float C = expf(tt);
  const float sqi = sqv[i0 + g];

  float acc[16] = {};
  float lv[16];
  int lj[16];
#pragma unroll
  for (int u = 0; u < TK; ++u) { lv[u] = -3.0e38f; lj[u] = 0x7fffffff; }

  // prefetch subtile 0
  f4 pb[4];
#pragma unroll
  for (int qq = 0; qq < 4; ++qq)
    pb[qq] = *(const f4*)&hb[(size_t)jrow * DE + half * 16 + qq * 4];

  for (int s = 0; s < 256; ++s) {       // (jt = s>>3, k0 = (s&7)*32)
    __syncthreads();                    // LDS Hb free
    {
      const int kqb = half * 4;
      const int swzw = (jrow >> 3) & 7;
#pragma unroll
      for (int qq = 0; qq < 4; ++qq)
        *(f4*)&Hb[jrow][((kqb + qq) ^ swzw) * 4] = pb[qq];
    }
    if (s + 1 < 256) {
      const int jt1 = (s + 1) >> 3, k01 = ((s + 1) & 7) * 32;
#pragma unroll
      for (int qq = 0; qq < 4; ++qq)
        pb[qq] = *(const f4*)&hb[(size_t)(jt1 * 256 + jrow) * DE + k01 + half * 16 + qq * 4];
    }
    __syncthreads();                    // Hb ready
    const int k0 = (s & 7) * 32;
#pragma unroll
    for (int k4 = 0; k4 < 8; ++k4) {
      f4 av = *(const f4*)&Ha[g][k0 + k4 * 4];
      const float* af = (const float*)&av;
      f4 bv[16];
#pragma unroll
      for (int mb = 0; mb < 4; ++mb)
#pragma unroll
        for (int e = 0; e < 4; ++e)
          bv[mb * 4 + e] = *(const f4*)&Hb[cg * 4 + 64 * mb + e][(k4 ^ swzc) * 4];
#pragma unroll
      for (int qq = 0; qq < 4; ++qq) {
#pragma unroll
        for (int idx = 0; idx < 16; ++idx) {
          const float* bf = (const float*)&bv[idx];
          acc[idx] = __fmaf_rn(af[qq], bf[qq], acc[idx]);
        }
      }
    }
    if ((s & 7) == 7) {
      const int j0s = (s >> 3) * 256;
      // scores (instruction-identical to the round-4 passing formula)
#pragma unroll
      for (int mb = 0; mb < 4; ++mb) {
        f4 sqj = *(const f4*)&sqv[j0s + cg * 4 + 64 * mb];
        f4 qv = *(const f4*)&q[(size_t)(i0 + g) * NN + j0s + cg * 4 + 64 * mb];
        const float* sqjf = (const float*)&sqj;
        const float* qvf = (const float*)&qv;
        f4 sv;
        float* svf = (float*)&sv;
#pragma unroll
        for (int e = 0; e < 4; ++e) {
          const float t1 = __fadd_rn(sqi, sqjf[e]);
          float D = __fsub_rn(t1, __fmul_rn(2.0f, acc[mb * 4 + e]));
          D = fmaxf(D, 0.0f);
          const float lg = __fmul_rn(D, C);
          const float p = __fadd_rn(qvf[e], 1e-8f);
          const float u = logf(p);
          const float nv = logf(-u);
          svf[e] = __fsub_rn(nv, lg);
        }
        *(f4*)&sc[g][cg * 4 + 64 * mb] = sv;
      }
#pragma unroll
      for (int u = 0; u < 16; ++u) acc[u] = 0.0f;
      __syncthreads();                  // sc ready
      // selection: ascending j within selector (j = j0s + c*16 + s)
      for (int c = 0; c < 16; ++c) {
        const float v = sc[g][c * 16 + cg];
        if (v > lv[15]) {               // strict: ties keep earlier (smaller) j
          float cv = v;
          int cj = j0s + c * 16 + cg;
#pragma unroll
          for (int u = 0; u < TK; ++u) {
            const bool take = (cv > lv[u]);
            const float nv2 = take ? cv : lv[u];
            const int nj2 = take ? cj : lj[u];
            cv = take ? lv[u] : cv;
            cj = take ? lj[u] : cj;
            lv[u] = nv2;
            lj[u] = nj2;
          }
        }
      }
    }
  }

  // ---- merge: dump sorted lists, then 16-way sorted merge per row ----
  __syncthreads();
  float* mv = &Ha[0][0];   // 8192 floats
  int* mj = (int*)&Hb[0][0];  // 8192 ints
#pragma unroll
  for (int u = 0; u < TK; ++u) {
    mv[tid * TK + u] = lv[u];
    mj[tid * TK + u] = lj[u];
  }
  __syncthreads();
  if (tid < 32) {
    const int r = tid;
    for (int s2 = 0; s2 < 16; ++s2) curs[r][s2] = 0;
    float* E0 = out + (size_t)NN * DE;
    float* E1 = E0 + (size_t)NN * TK;
    float* LP = E1 + (size_t)NN * TK;
    for (int it = 0; it < TK; ++it) {
      float bvv = -3.0e38f;
      int bj = 0x7fffffff, bs = 0;
      for (int s2 = 0; s2 < 16; ++s2) {
        const int cu = curs[r][s2];
        if (cu < TK) {
          const float v = mv[(r * 16 + s2) * TK + cu];
          const int jx = mj[(r * 16 + s2) * TK + cu];
          if (v > bvv || (v == bvv && jx < bj)) { bvv = v; bj = jx; bs = s2; }
        }
      }
      curs[r][bs]++;
      E0[(size_t)(i0 + r) * TK + it] = (float)bj;
      E1[(size_t)(i0 + r) * TK + it] = (float)(i0 + r);
      LP[(size_t)(i0 + r) * TK + it] = bvv;
    }
  }
}

extern "C" void kernel_launch(void* const* d_in, const int* in_sizes, int n_in,
                              void* d_out, int out_size, void* d_ws, size_t ws_size,
                              hipStream_t stream) {
  const float* x = (const float*)d_in[0];
  const float* A = (const float*)d_in[1];
  const float* W = (const float*)d_in[2];
  const float* temp = (const float*)d_in[3];
  const float* q = (const float*)d_in[4];
  float* out = (float*)d_out;

  char* ws = (char*)d_ws;
  float* xw = (float*)(ws);            // 8,388,608 B
  float* sq = (float*)(ws + 8388608);  //    32,768 B

  float* hb = out;  // [N, DE] f32 output region holds h

  hipLaunchKernelGGL((k_gemm<DI, false>), dim3(NN / 32), dim3(512), 0, stream, x, DI, W, xw);
  hipLaunchKernelGGL((k_gemm<NN, true>), dim3(NN / 32), dim3(512), 0, stream, A, NN, xw, hb);
  hipLaunchKernelGGL(k_sq32, dim3(NN / 256), dim3(256), 0, stream, hb, sq);
  hipLaunchKernelGGL(k_sel, dim3(NN / 32), dim3(512), 0, stream, hb, sq, q, temp, out);
}

// Round 6
// 2162.175 us; speedup vs baseline: 3.7027x; 1.2379x over previous
//
#include <hip/hip_runtime.h>
#include <math.h>

// DGM edge sampler, N=8192, DIN=512, DEMB=256, K=16.
// Canonical-f32 pipeline (bit-faithful to the np reference): k-ascending FMA
// GEMMs, numpy-pairwise row sums, explicit __f*_rn at every op boundary.
// Round 6: k_sel rebuilt as canonical GEMM via hbT (transposed h):
//  - B-fragment LDS reads are stride-1 b128 (conflict-free baseline)
//  - A-fragment LDS reads are full-wave broadcasts (free)
//  - 4x4 per-thread tile: 8 b128 reads / 64 FMAs (LDS-vs-VALU balanced)

#define NN 8192
#define DI 512
#define DE 256
#define TK 16

typedef float4 f4;

// ======== K1/K2: C = [relu](Amat @ Bmat), Bmat is [KTOT][256] ========
template <int KTOT, bool RELU>
__global__ __launch_bounds__(512) void k_gemm(const float* __restrict__ Amat, int lda,
                                              const float* __restrict__ Bmat,
                                              float* __restrict__ Cout) {
  __shared__ float As[32][32];   // 4 KB
  __shared__ float Bs[32][256];  // 32 KB
  const int i0 = blockIdx.x * 32;
  const int tid = threadIdx.x;
  const int g = tid >> 5;
  const int cg = tid & 31;
  const int arow = tid >> 3, aq = tid & 7;
  const int bkk = tid >> 4, bq = tid & 15;
  float acc[2][8] = {};
  f4 pa;
  f4 pb[4];
  if (tid < 256) pa = *(const f4*)&Amat[(size_t)(i0 + arow) * lda + aq * 4];
#pragma unroll
  for (int l = 0; l < 4; ++l)
    pb[l] = *(const f4*)&Bmat[(size_t)bkk * DE + (bq + 16 * l) * 4];

  for (int k0 = 0; k0 < KTOT; k0 += 32) {
    __syncthreads();
    if (tid < 256) *(f4*)&As[arow][aq * 4] = pa;
#pragma unroll
    for (int l = 0; l < 4; ++l) *(f4*)&Bs[bkk][(bq + 16 * l) * 4] = pb[l];
    if (k0 + 32 < KTOT) {
      if (tid < 256) pa = *(const f4*)&Amat[(size_t)(i0 + arow) * lda + k0 + 32 + aq * 4];
#pragma unroll
      for (int l = 0; l < 4; ++l)
        pb[l] = *(const f4*)&Bmat[(size_t)(k0 + 32 + bkk) * DE + (bq + 16 * l) * 4];
    }
    __syncthreads();
#pragma unroll
    for (int k4 = 0; k4 < 8; ++k4) {
      f4 a0 = *(const f4*)&As[g * 2 + 0][k4 * 4];
      f4 a1 = *(const f4*)&As[g * 2 + 1][k4 * 4];
      const float* a0f = (const float*)&a0;
      const float* a1f = (const float*)&a1;
#pragma unroll
      for (int qq = 0; qq < 4; ++qq) {
        f4 b0 = *(const f4*)&Bs[k4 * 4 + qq][cg * 4];
        f4 b1 = *(const f4*)&Bs[k4 * 4 + qq][128 + cg * 4];
        const float* b0f = (const float*)&b0;
        const float* b1f = (const float*)&b1;
#pragma unroll
        for (int m = 0; m < 4; ++m) {
          acc[0][m] = __fmaf_rn(a0f[qq], b0f[m], acc[0][m]);
          acc[1][m] = __fmaf_rn(a1f[qq], b0f[m], acc[1][m]);
          acc[0][4 + m] = __fmaf_rn(a0f[qq], b1f[m], acc[0][4 + m]);
          acc[1][4 + m] = __fmaf_rn(a1f[qq], b1f[m], acc[1][4 + m]);
        }
      }
    }
  }
#pragma unroll
  for (int u = 0; u < 2; ++u) {
    const int i = i0 + g * 2 + u;
    f4 o0, o1;
    float* o0f = (float*)&o0;
    float* o1f = (float*)&o1;
#pragma unroll
    for (int m = 0; m < 4; ++m) {
      o0f[m] = RELU ? fmaxf(acc[u][m], 0.0f) : acc[u][m];
      o1f[m] = RELU ? fmaxf(acc[u][4 + m], 0.0f) : acc[u][4 + m];
    }
    *(f4*)&Cout[(size_t)i * DE + cg * 4] = o0;
    *(f4*)&Cout[(size_t)i * DE + 128 + cg * 4] = o1;
  }
}

// ======== K2b: hbT[k][i] = hb[i][k]  (64x64 LDS tiles, pad 65) ========
__global__ __launch_bounds__(256) void k_tr(const float* __restrict__ hb,
                                            float* __restrict__ hbT) {
  __shared__ float t[64][65];
  const int i0 = blockIdx.x * 64;
  const int k0 = blockIdx.y * 64;
  const int tid = threadIdx.x;
#pragma unroll
  for (int l = 0; l < 4; ++l) {
    const int lin = tid + 256 * l;       // 1024 f4
    const int r = lin >> 4, cq = lin & 15;
    f4 v = *(const f4*)&hb[(size_t)(i0 + r) * DE + k0 + cq * 4];
    const float* vf = (const float*)&v;
#pragma unroll
    for (int w = 0; w < 4; ++w) t[r][cq * 4 + w] = vf[w];
  }
  __syncthreads();
#pragma unroll
  for (int l = 0; l < 4; ++l) {
    const int kk = (tid >> 4) + 16 * l;  // 0..63
    const int iq = tid & 15;
    f4 o;
    float* of = (float*)&o;
#pragma unroll
    for (int w = 0; w < 4; ++w) of[w] = t[iq * 4 + w][kk];
    *(f4*)&hbT[(size_t)(k0 + kk) * NN + i0 + iq * 4] = o;
  }
}

// ======== K3: sq[i] = sum(h_i*h_i), numpy-pairwise structure ========
__global__ __launch_bounds__(256) void k_sq32(const float* __restrict__ hb,
                                              float* __restrict__ sq) {
  const int row = blockIdx.x * 256 + threadIdx.x;
  const float* h = hb + (size_t)row * DE;
  float half[2];
#pragma unroll
  for (int hx = 0; hx < 2; ++hx) {
    float p[8] = {};
    for (int t = 0; t < 16; ++t) {
      f4 v0 = *(const f4*)&h[hx * 128 + t * 8];
      f4 v1 = *(const f4*)&h[hx * 128 + t * 8 + 4];
      const float* v0f = (const float*)&v0;
      const float* v1f = (const float*)&v1;
#pragma unroll
      for (int m = 0; m < 4; ++m) {
        p[m] = __fadd_rn(p[m], __fmul_rn(v0f[m], v0f[m]));
        p[4 + m] = __fadd_rn(p[4 + m], __fmul_rn(v1f[m], v1f[m]));
      }
    }
    const float t01 = __fadd_rn(p[0], p[1]), t23 = __fadd_rn(p[2], p[3]);
    const float t45 = __fadd_rn(p[4], p[5]), t67 = __fadd_rn(p[6], p[7]);
    half[hx] = __fadd_rn(__fadd_rn(t01, t23), __fadd_rn(t45, t67));
  }
  sq[row] = __fadd_rn(half[0], half[1]);
}

// ======== K4: fused f32 scoring + parallel streaming top-16 ========
// block: 32 rows x j-tile 256, 512 threads.
// compute thread: rg=tid>>6 (rows rg*4..+3, A-reads wave-broadcast),
//                 cq=tid&63 (cols cq*4..+3, B-reads stride-1 b128).
// selector thread: (g=tid>>4 row, cg=tid&15), register sorted top-16.
__global__ __launch_bounds__(512) void k_sel(const float* __restrict__ hb,
                                             const float* __restrict__ hbT,
                                             const float* __restrict__ sqv,
                                             const float* __restrict__ q,
                                             const float* __restrict__ temp,
                                             float* __restrict__ out) {
  __shared__ float Ha[32][260];  // 33.3 KB  (merge mv at end)
  __shared__ float Bs[32][260];  // 33.3 KB  (merge mj at end)
  __shared__ float sc[32][260];  // 33.3 KB
  __shared__ int curs[32][16];   // 2 KB
  const int i0 = blockIdx.x * 32;
  const int tid = threadIdx.x;
  const int rg = tid >> 6;       // 0..7
  const int cq = tid & 63;       // 0..63
  const int r0 = rg * 4;
  const int g = tid >> 4;        // selector row
  const int cg = tid & 15;       // selector sub-index

  // Ha: 32 rows x 256 (resident whole kernel)
#pragma unroll
  for (int w = 0; w < 4; ++w) {
    const int lin = tid + 512 * w;
    const int row = lin >> 6, part = lin & 63;
    *(f4*)&Ha[row][part * 4] = *(const f4*)&hb[(size_t)(i0 + row) * DE + part * 4];
  }
  const float tt = fminf(fmaxf(temp[0], -5.0f), 5.0f);
  const float C = expf(tt);
  float sqi[4];
#pragma unroll
  for (int u = 0; u < 4; ++u) sqi[u] = sqv[i0 + r0 + u];

  float acc[4][4] = {};
  float lv[16];
  int lj[16];
#pragma unroll
  for (int u = 0; u < TK; ++u) { lv[u] = -3.0e38f; lj[u] = 0x7fffffff; }

  // prefetch chunk 0 (jt=0, kc=0): Bs source = hbT[k][j]
  f4 pb[4];
#pragma unroll
  for (int w = 0; w < 4; ++w) {
    const int lin = tid + 512 * w;
    const int krow = lin >> 6, jq = lin & 63;
    pb[w] = *(const f4*)&hbT[(size_t)krow * NN + jq * 4];
  }

  for (int s = 0; s < 256; ++s) {  // jt = s>>3, kc = s&7
    __syncthreads();               // Bs free (prev compute / selection done)
#pragma unroll
    for (int w = 0; w < 4; ++w) {
      const int lin = tid + 512 * w;
      *(f4*)&Bs[lin >> 6][(lin & 63) * 4] = pb[w];
    }
    if (s + 1 < 256) {
      const int jt1 = (s + 1) >> 3, kc1 = (s + 1) & 7;
#pragma unroll
      for (int w = 0; w < 4; ++w) {
        const int lin = tid + 512 * w;
        const int krow = lin >> 6, jq = lin & 63;
        pb[w] = *(const f4*)&hbT[(size_t)(kc1 * 32 + krow) * NN + jt1 * 256 + jq * 4];
      }
    }
    __syncthreads();               // Bs ready
    const int kbase = (s & 7) * 32;
#pragma unroll
    for (int k4 = 0; k4 < 8; ++k4) {
      f4 av[4];
#pragma unroll
      for (int u = 0; u < 4; ++u)
        av[u] = *(const f4*)&Ha[r0 + u][kbase + k4 * 4];  // wave-broadcast
#pragma unroll
      for (int kk = 0; kk < 4; ++kk) {                    // k ascending
        f4 b = *(const f4*)&Bs[k4 * 4 + kk][cq * 4];      // stride-1 b128
        const float* bf = (const float*)&b;
#pragma unroll
        for (int u = 0; u < 4; ++u) {
          const float a = ((const float*)&av[u])[kk];
#pragma unroll
          for (int m = 0; m < 4; ++m)
            acc[u][m] = __fmaf_rn(a, bf[m], acc[u][m]);
        }
      }
    }
    if ((s & 7) == 7) {
      const int j0s = (s >> 3) * 256;
      // scores (instruction-identical to the round-4 passing formula)
      f4 sqj = *(const f4*)&sqv[j0s + cq * 4];
      const float* sqjf = (const float*)&sqj;
#pragma unroll
      for (int u = 0; u < 4; ++u) {
        const int i = i0 + r0 + u;
        f4 qv = *(const f4*)&q[(size_t)i * NN + j0s + cq * 4];
        const float* qvf = (const float*)&qv;
        f4 sv;
        float* svf = (float*)&sv;
#pragma unroll
        for (int e = 0; e < 4; ++e) {
          const float t1 = __fadd_rn(sqi[u], sqjf[e]);
          float D = __fsub_rn(t1, __fmul_rn(2.0f, acc[u][e]));
          D = fmaxf(D, 0.0f);
          const float lg = __fmul_rn(D, C);
          const float p = __fadd_rn(qvf[e], 1e-8f);
          const float uu = logf(p);
          const float nv = logf(-uu);
          svf[e] = __fsub_rn(nv, lg);
          acc[u][e] = 0.0f;
        }
        *(f4*)&sc[r0 + u][cq * 4] = sv;
      }
      __syncthreads();             // sc ready
      // selection: ascending j within selector (j = j0s + c*16 + cg)
      for (int c = 0; c < 16; ++c) {
        const float v = sc[g][c * 16 + cg];
        if (v > lv[15]) {          // strict: ties keep earlier (smaller) j
          float cv = v;
          int cj = j0s + c * 16 + cg;
#pragma unroll
          for (int u = 0; u < TK; ++u) {
            const bool take = (cv > lv[u]);
            const float nv2 = take ? cv : lv[u];
            const int nj2 = take ? cj : lj[u];
            cv = take ? lv[u] : cv;
            cj = take ? lj[u] : cj;
            lv[u] = nv2;
            lj[u] = nj2;
          }
        }
      }
    }
  }

  // ---- merge: dump sorted lists, 16-way sorted merge per row ----
  __syncthreads();
  float* mv = &Ha[0][0];      // 512*16 floats = 32 KB (fits 33.3 KB)
  int* mj = (int*)&Bs[0][0];  // 512*16 ints
#pragma unroll
  for (int u = 0; u < TK; ++u) {
    mv[tid * TK + u] = lv[u];
    mj[tid * TK + u] = lj[u];
  }
  __syncthreads();
  if (tid < 32) {
    const int r = tid;
    for (int s2 = 0; s2 < 16; ++s2) curs[r][s2] = 0;
    float* E0 = out + (size_t)NN * DE;
    float* E1 = E0 + (size_t)NN * TK;
    float* LP = E1 + (size_t)NN * TK;
    for (int it = 0; it < TK; ++it) {
      float bvv = -3.0e38f;
      int bj = 0x7fffffff, bs = 0;
      for (int s2 = 0; s2 < 16; ++s2) {
        const int cu = curs[r][s2];
        if (cu < TK) {
          const float v = mv[(r * 16 + s2) * TK + cu];
          const int jx = mj[(r * 16 + s2) * TK + cu];
          if (v > bvv || (v == bvv && jx < bj)) { bvv = v; bj = jx; bs = s2; }
        }
      }
      curs[r][bs]++;
      E0[(size_t)(i0 + r) * TK + it] = (float)bj;
      E1[(size_t)(i0 + r) * TK + it] = (float)(i0 + r);
      LP[(size_t)(i0 + r) * TK + it] = bvv;
    }
  }
}

extern "C" void kernel_launch(void* const* d_in, const int* in_sizes, int n_in,
                              void* d_out, int out_size, void* d_ws, size_t ws_size,
                              hipStream_t stream) {
  const float* x = (const float*)d_in[0];
  const float* A = (const float*)d_in[1];
  const float* W = (const float*)d_in[2];
  const float* temp = (const float*)d_in[3];
  const float* q = (const float*)d_in[4];
  float* out = (float*)d_out;

  char* ws = (char*)d_ws;
  float* xw = (float*)(ws);             //  8,388,608 B
  float* sq = (float*)(ws + 8388608);   //     32,768 B
  float* hbT = (float*)(ws + 8421376);  //  8,388,608 B  [256][8192]

  float* hb = out;  // [N, DE] f32 output region holds h

  hipLaunchKernelGGL((k_gemm<DI, false>), dim3(NN / 32), dim3(512), 0, stream, x, DI, W, xw);
  hipLaunchKernelGGL((k_gemm<NN, true>), dim3(NN / 32), dim3(512), 0, stream, A, NN, xw, hb);
  hipLaunchKernelGGL(k_tr, dim3(NN / 64, DE / 64), dim3(256), 0, stream, hb, hbT);
  hipLaunchKernelGGL(k_sq32, dim3(NN / 256), dim3(256), 0, stream, hb, sq);
  hipLaunchKernelGGL(k_sel, dim3(NN / 32), dim3(512), 0, stream, hb, hbT, sq, q, temp, out);
}